// Round 1
// baseline (338.153 us; speedup 1.0000x reference)
//
#include <hip/hip_runtime.h>
#include <hip/hip_bf16.h>
#include <stdint.h>

typedef __bf16 bf16x8 __attribute__((ext_vector_type(8)));
typedef unsigned short ushort8 __attribute__((ext_vector_type(8)));
typedef unsigned short ushort4v __attribute__((ext_vector_type(4)));
typedef float f32x4 __attribute__((ext_vector_type(4)));

#define MFMA16(a, b, c) __builtin_amdgcn_mfma_f32_16x16x32_bf16((a), (b), (c), 0, 0, 0)

__device__ __forceinline__ unsigned short f2bf(float f) {
    uint32_t u = __float_as_uint(f);
    u += 0x7FFFu + ((u >> 16) & 1u);   // round-to-nearest-even
    return (unsigned short)(u >> 16);
}

// ---------------- kernel 1: x (fp32) -> xb (bf16), 16384x512 ----------------
__global__ void k_cvt_x(const float* __restrict__ x, unsigned short* __restrict__ xb) {
    int t = blockIdx.x * 256 + threadIdx.x;       // exactly 2097152 float4s
    f32x4 v = ((const f32x4*)x)[t];
    ushort4v o;
    o[0] = f2bf(v[0]); o[1] = f2bf(v[1]); o[2] = f2bf(v[2]); o[3] = f2bf(v[3]);
    ((ushort4v*)xb)[t] = o;
}

// ------- kernel 2: pack Wt[640][512] = [W1|W2|W3]^T in bf16 (B-operand) ------
__global__ void k_build_wt(const float* __restrict__ W1, const float* __restrict__ W2,
                           const float* __restrict__ W3, unsigned short* __restrict__ Wt) {
    int idx = blockIdx.x * 256 + threadIdx.x;     // 0 .. 327679
    int n = idx >> 9;                              // output col 0..639
    int k = idx & 511;                             // input channel
    float v;
    if (n < 64)       v = W1[k * 64 + n];
    else if (n < 128) v = W2[k * 64 + (n - 64)];
    else              v = W3[k * 512 + (n - 128)];
    Wt[idx] = f2bf(v);
}

// -------- kernel 3: QKV projection GEMM, M=16384 K=512 N=640 (bf16 MFMA) -----
// Q[b*4096+i][64], K[b*4096+i][64] row-major; V stored transposed Vt[b][c][j].
__global__ __launch_bounds__(256) void k_proj(const unsigned short* __restrict__ xb,
                                              const unsigned short* __restrict__ Wt,
                                              unsigned short* __restrict__ Qb,
                                              unsigned short* __restrict__ Kb,
                                              unsigned short* __restrict__ Vt) {
    const int lane = threadIdx.x & 63;
    const int w    = threadIdx.x >> 6;
    const int m0   = blockIdx.x * 64;
    const int n0   = blockIdx.y * 64 + w * 16;    // wave-uniform 16-col slice
    const int col  = lane & 15, quad = lane >> 4;

    f32x4 acc[4] = {};
    const unsigned short* a0 = xb + (m0 + col) * 512 + quad * 8;
    const unsigned short* b0 = Wt + (n0 + col) * 512 + quad * 8;

    for (int k = 0; k < 512; k += 32) {
        bf16x8 bf = *(const bf16x8*)(b0 + k);
#pragma unroll
        for (int it = 0; it < 4; ++it) {
            bf16x8 af = *(const bf16x8*)(a0 + it * 16 * 512 + k);
            acc[it] = MFMA16(af, bf, acc[it]);
        }
    }

    if (n0 < 128) {                                // Q or K slab (wave-uniform)
        unsigned short* dst = (n0 < 64) ? Qb : Kb;
        int nc = (n0 < 64) ? (n0 + col) : (n0 - 64 + col);
#pragma unroll
        for (int it = 0; it < 4; ++it) {
            int ig = m0 + it * 16 + quad * 4;      // global row (= b*4096+i)
#pragma unroll
            for (int r = 0; r < 4; ++r)
                dst[(ig + r) * 64 + nc] = f2bf(acc[it][r]);
        }
    } else {                                       // V slab -> transposed Vt[c][i]
        int vrow = n0 - 128 + col;
#pragma unroll
        for (int it = 0; it < 4; ++it) {
            int ig = m0 + it * 16 + quad * 4;
            int b = ig >> 12, ii = ig & 4095;
            ushort4v pk;
#pragma unroll
            for (int r = 0; r < 4; ++r) pk[r] = f2bf(acc[it][r]);
            *(ushort4v*)(Vt + ((b * 512 + vrow) << 12) + ii) = pk;
        }
    }
}

// ---------------- kernel 4: flash attention + scrambled epilogue -------------
// 1 WG = 512 thr (8 waves) per 64-row Q tile. wave w owns V columns [64w,64w+64).
__global__ __launch_bounds__(512, 2) void k_flash(const unsigned short* __restrict__ Qb,
                                                  const unsigned short* __restrict__ Kb,
                                                  const unsigned short* __restrict__ Vt,
                                                  const float* __restrict__ x,
                                                  const float* __restrict__ gamma,
                                                  float* __restrict__ out) {
    __shared__ __align__(16) unsigned short Qs[64 * 72];   // Q tile, padded stride
    __shared__ __align__(16) float          Ss[64 * 132];  // scores fp32
    __shared__ __align__(16) unsigned short Ps[64 * 136];  // exp(S) bf16
    __shared__ float m_s[64], l_s[64], al_s[64];

    const int tid  = threadIdx.x;
    const int lane = tid & 63;
    const int w    = tid >> 6;
    const int col  = lane & 15, quad = lane >> 4;
    const int b    = blockIdx.x >> 6;
    const int i0   = (blockIdx.x & 63) * 64;

    const unsigned short* Qbase = Qb + (b * 4096 + i0) * 64;
    const unsigned short* Kbase = Kb + b * 4096 * 64;
    const unsigned short* Vbase = Vt + b * 512 * 4096;

    if (tid < 64) { m_s[tid] = -3.0e38f; l_s[tid] = 0.0f; }
    {   // stage Q tile (coalesced 16B per thread)
        int row = tid >> 3, ch = tid & 7;
        *(ushort8*)(&Qs[row * 72 + ch * 8]) = *(const ushort8*)(Qbase + row * 64 + ch * 8);
    }
    __syncthreads();

    bf16x8 qf[4][2];
#pragma unroll
    for (int it = 0; it < 4; ++it) {
        qf[it][0] = *(const bf16x8*)(&Qs[(it * 16 + col) * 72 + quad * 8]);
        qf[it][1] = *(const bf16x8*)(&Qs[(it * 16 + col) * 72 + 32 + quad * 8]);
    }

    f32x4 acc[4][4] = {};

    for (int j0 = 0; j0 < 4096; j0 += 128) {
        // prefetch V B-fragments for the PV stage (in flight across S+softmax)
        bf16x8 vf[4][4];
#pragma unroll
        for (int ct = 0; ct < 4; ++ct) {
            const unsigned short* vp = Vbase + (w * 64 + ct * 16 + col) * 4096 + j0 + quad * 8;
#pragma unroll
            for (int kk = 0; kk < 4; ++kk) vf[ct][kk] = *(const bf16x8*)(vp + kk * 32);
        }
        // ---- S = Q·K^T : wave w computes score cols [j0+16w, j0+16w+16) ----
        {
            const unsigned short* kp = Kbase + (j0 + w * 16 + col) * 64 + quad * 8;
            bf16x8 kf0 = *(const bf16x8*)(kp);
            bf16x8 kf1 = *(const bf16x8*)(kp + 32);
#pragma unroll
            for (int it = 0; it < 4; ++it) {
                f32x4 s = {};
                s = MFMA16(qf[it][0], kf0, s);
                s = MFMA16(qf[it][1], kf1, s);
                int rb = it * 16 + quad * 4;
#pragma unroll
                for (int r = 0; r < 4; ++r) Ss[(rb + r) * 132 + w * 16 + col] = s[r];
            }
        }
        __syncthreads();
        // ---- online softmax over the 64x128 tile (8 threads per row) ----
        {
            int row = tid >> 3, g = tid & 7;
            float* sp = &Ss[row * 132 + g * 16];
            f32x4 v0 = *(f32x4*)(sp + 0);
            f32x4 v1 = *(f32x4*)(sp + 4);
            f32x4 v2 = *(f32x4*)(sp + 8);
            f32x4 v3 = *(f32x4*)(sp + 12);
            float mx = fmaxf(fmaxf(fmaxf(v0[0], v0[1]), fmaxf(v0[2], v0[3])),
                             fmaxf(fmaxf(v1[0], v1[1]), fmaxf(v1[2], v1[3])));
            mx = fmaxf(mx, fmaxf(fmaxf(fmaxf(v2[0], v2[1]), fmaxf(v2[2], v2[3])),
                                 fmaxf(fmaxf(v3[0], v3[1]), fmaxf(v3[2], v3[3]))));
            mx = fmaxf(mx, __shfl_xor(mx, 1, 8));
            mx = fmaxf(mx, __shfl_xor(mx, 2, 8));
            mx = fmaxf(mx, __shfl_xor(mx, 4, 8));
            float mo = m_s[row];
            float mn = fmaxf(mo, mx);
            float al = __expf(mo - mn);
            f32x4 e0, e1, e2, e3;
#pragma unroll
            for (int i = 0; i < 4; ++i) {
                e0[i] = __expf(v0[i] - mn); e1[i] = __expf(v1[i] - mn);
                e2[i] = __expf(v2[i] - mn); e3[i] = __expf(v3[i] - mn);
            }
            float sum = (e0[0]+e0[1]+e0[2]+e0[3]) + (e1[0]+e1[1]+e1[2]+e1[3])
                      + (e2[0]+e2[1]+e2[2]+e2[3]) + (e3[0]+e3[1]+e3[2]+e3[3]);
            ushort8 p0, p1;
#pragma unroll
            for (int i = 0; i < 4; ++i) {
                p0[i]     = f2bf(e0[i]); p0[i + 4] = f2bf(e1[i]);
                p1[i]     = f2bf(e2[i]); p1[i + 4] = f2bf(e3[i]);
            }
            *(ushort8*)(&Ps[row * 136 + g * 16])     = p0;
            *(ushort8*)(&Ps[row * 136 + g * 16 + 8]) = p1;
            sum += __shfl_xor(sum, 1, 8);
            sum += __shfl_xor(sum, 2, 8);
            sum += __shfl_xor(sum, 4, 8);
            if (g == 0) { m_s[row] = mn; l_s[row] = al * l_s[row] + sum; al_s[row] = al; }
        }
        __syncthreads();
        // ---- rescale O and accumulate P·V ----
#pragma unroll
        for (int it = 0; it < 4; ++it) {
            int rb = it * 16 + quad * 4;
            f32x4 av;
            av[0] = al_s[rb]; av[1] = al_s[rb + 1]; av[2] = al_s[rb + 2]; av[3] = al_s[rb + 3];
#pragma unroll
            for (int ct = 0; ct < 4; ++ct) acc[it][ct] *= av;
        }
#pragma unroll
        for (int it = 0; it < 4; ++it) {
            bf16x8 pf[4];
#pragma unroll
            for (int kk = 0; kk < 4; ++kk)
                pf[kk] = *(const bf16x8*)(&Ps[(it * 16 + col) * 136 + kk * 32 + quad * 8]);
#pragma unroll
            for (int ct = 0; ct < 4; ++ct)
#pragma unroll
                for (int kk = 0; kk < 4; ++kk)
                    acc[it][ct] = MFMA16(pf[kk], vf[ct][kk], acc[it][ct]);
        }
        // no barrier needed here: next S-write fenced from this softmax's reads
        // by the post-softmax barrier; next P-write fenced by next pre-softmax barrier.
    }

    // ---- epilogue: out[f] = gamma*O[i,c]/l + x[f], f = c*4096 + i (raw reshape) ----
    const float gam = gamma[0];
    const float* xb_ = x + b * 2097152;
    float* ob_ = out + b * 2097152;
#pragma unroll
    for (int it = 0; it < 4; ++it) {
        int rb = it * 16 + quad * 4;
        f32x4 li;
        li[0] = 1.0f / l_s[rb];     li[1] = 1.0f / l_s[rb + 1];
        li[2] = 1.0f / l_s[rb + 2]; li[3] = 1.0f / l_s[rb + 3];
#pragma unroll
        for (int ct = 0; ct < 4; ++ct) {
            int cg = w * 64 + ct * 16 + col;
            int f = cg * 4096 + i0 + rb;          // 16B-aligned, r gives contiguous floats
            f32x4 xv = *(const f32x4*)(xb_ + f);
            f32x4 a = acc[it][ct];
            f32x4 o;
            o[0] = gam * a[0] * li[0] + xv[0];
            o[1] = gam * a[1] * li[1] + xv[1];
            o[2] = gam * a[2] * li[2] + xv[2];
            o[3] = gam * a[3] * li[3] + xv[3];
            *(f32x4*)(ob_ + f) = o;
        }
    }
}

extern "C" void kernel_launch(void* const* d_in, const int* in_sizes, int n_in,
                              void* d_out, int out_size, void* d_ws, size_t ws_size,
                              hipStream_t stream) {
    const float* x  = (const float*)d_in[0];
    const float* W1 = (const float*)d_in[1];
    const float* W2 = (const float*)d_in[2];
    const float* W3 = (const float*)d_in[3];
    const float* gm = (const float*)d_in[4];
    float* out = (float*)d_out;

    char* ws = (char*)d_ws;
    unsigned short* xb = (unsigned short*)(ws);                       // 16 MiB
    unsigned short* Wt = (unsigned short*)(ws + 16777216);            // 640 KiB
    unsigned short* Qb = (unsigned short*)(ws + 16777216 + 655360);   // 2 MiB
    unsigned short* Kb = (unsigned short*)(ws + 16777216 + 655360 + 2097152);
    unsigned short* Vt = (unsigned short*)(ws + 16777216 + 655360 + 2 * 2097152); // 16 MiB
    // total workspace use: ~38.4 MB

    hipLaunchKernelGGL(k_cvt_x,    dim3(8192),    dim3(256), 0, stream, x, xb);
    hipLaunchKernelGGL(k_build_wt, dim3(1280),    dim3(256), 0, stream, W1, W2, W3, Wt);
    hipLaunchKernelGGL(k_proj,     dim3(256, 10), dim3(256), 0, stream, xb, Wt, Qb, Kb, Vt);
    hipLaunchKernelGGL(k_flash,    dim3(256),     dim3(512), 0, stream, Qb, Kb, Vt, x, gm, out);
}

// Round 3
// 283.838 us; speedup vs baseline: 1.1914x; 1.1914x over previous
//
#include <hip/hip_runtime.h>
#include <hip/hip_bf16.h>
#include <stdint.h>

typedef __bf16 bf16x8 __attribute__((ext_vector_type(8)));
typedef unsigned short ushort8 __attribute__((ext_vector_type(8)));
typedef unsigned short ushort4v __attribute__((ext_vector_type(4)));
typedef float f32x4 __attribute__((ext_vector_type(4)));

#define MFMA16(a, b, c) __builtin_amdgcn_mfma_f32_16x16x32_bf16((a), (b), (c), 0, 0, 0)

__device__ __forceinline__ unsigned short f2bf(float f) {
    uint32_t u = __float_as_uint(f);
    u += 0x7FFFu + ((u >> 16) & 1u);   // round-to-nearest-even
    return (unsigned short)(u >> 16);
}
__device__ __forceinline__ float bf2f(unsigned short u) {
    return __uint_as_float(((uint32_t)u) << 16);
}

// ------- kernel 1: pack Wt[640][512] = [W1|W2|W3]^T in bf16 (B-operand) ------
__global__ void k_build_wt(const float* __restrict__ W1, const float* __restrict__ W2,
                           const float* __restrict__ W3, unsigned short* __restrict__ Wt) {
    int idx = blockIdx.x * 256 + threadIdx.x;     // 0 .. 327679
    int n = idx >> 9;                              // output col 0..639
    int k = idx & 511;                             // input channel
    float v;
    if (n < 64)       v = W1[k * 64 + n];
    else if (n < 128) v = W2[k * 64 + (n - 64)];
    else              v = W3[k * 512 + (n - 128)];
    Wt[idx] = f2bf(v);
}

// -------- kernel 2: QKV projection GEMM, M=16384 K=512 N=640 (bf16 MFMA) -----
// LDS-staged A (fp32 x -> bf16), each of 8 waves owns 80 N-cols (5 x 16-tiles).
// Q[b*4096+i][64], K[b*4096+i][64] row-major; V stored transposed Vt[b][c][j].
__global__ __launch_bounds__(512, 2) void k_proj(const float* __restrict__ x,
                                                 const unsigned short* __restrict__ Wt,
                                                 unsigned short* __restrict__ Qb,
                                                 unsigned short* __restrict__ Kb,
                                                 unsigned short* __restrict__ Vt) {
    __shared__ __align__(16) unsigned short As[64 * 520];
    const int tid  = threadIdx.x;
    const int lane = tid & 63;
    const int w    = tid >> 6;
    const int m0   = blockIdx.x * 64;
    const int col  = lane & 15, quad = lane >> 4;

    // stage A tile: 64 rows x 512 ch, convert fp32 -> bf16
#pragma unroll
    for (int itr = 0; itr < 16; ++itr) {
        int idx = itr * 512 + tid;
        int row = idx >> 7, c4 = (idx & 127) << 2;
        f32x4 v = *(const f32x4*)(x + (m0 + row) * 512 + c4);
        ushort4v o;
        o[0] = f2bf(v[0]); o[1] = f2bf(v[1]); o[2] = f2bf(v[2]); o[3] = f2bf(v[3]);
        *(ushort4v*)(&As[row * 520 + c4]) = o;
    }
    __syncthreads();

    f32x4 acc[4][5] = {};
    bf16x8 bcur[5], bnxt[5];
    const unsigned short* bp = Wt + quad * 8;
#pragma unroll
    for (int nt = 0; nt < 5; ++nt)
        bcur[nt] = *(const bf16x8*)(bp + (w * 80 + nt * 16 + col) * 512);

    for (int k = 0; k < 16; ++k) {
        int kn = (k + 1) & 15;                     // prefetch next k-step's B frags
#pragma unroll
        for (int nt = 0; nt < 5; ++nt)
            bnxt[nt] = *(const bf16x8*)(bp + (w * 80 + nt * 16 + col) * 512 + kn * 32);
        bf16x8 af[4];
#pragma unroll
        for (int it = 0; it < 4; ++it)
            af[it] = *(const bf16x8*)(&As[(it * 16 + col) * 520 + k * 32 + quad * 8]);
#pragma unroll
        for (int it = 0; it < 4; ++it)
#pragma unroll
            for (int nt = 0; nt < 5; ++nt)
                acc[it][nt] = MFMA16(af[it], bcur[nt], acc[it][nt]);
#pragma unroll
        for (int nt = 0; nt < 5; ++nt) bcur[nt] = bnxt[nt];
    }

#pragma unroll
    for (int nt = 0; nt < 5; ++nt) {
        int n0 = w * 80 + nt * 16;                 // wave-uniform
        if (n0 < 128) {                            // Q or K slab
            unsigned short* dst = (n0 < 64) ? Qb : Kb;
            int nc = (n0 < 64) ? (n0 + col) : (n0 - 64 + col);
#pragma unroll
            for (int it = 0; it < 4; ++it) {
                int ig = m0 + it * 16 + quad * 4;
#pragma unroll
                for (int r = 0; r < 4; ++r)
                    dst[(ig + r) * 64 + nc] = f2bf(acc[it][nt][r]);
            }
        } else {                                   // V slab -> transposed Vt[c][i]
            int vrow = n0 - 128 + col;
#pragma unroll
            for (int it = 0; it < 4; ++it) {
                int ig = m0 + it * 16 + quad * 4;
                int b = ig >> 12, ii = ig & 4095;
                ushort4v pk;
#pragma unroll
                for (int r = 0; r < 4; ++r) pk[r] = f2bf(acc[it][nt][r]);
                *(ushort4v*)(Vt + ((b * 512 + vrow) << 12) + ii) = pk;
            }
        }
    }
}

// ---------------- kernel 3: flash attention over a j-half, partial output ----
// 512 WGs: bx&7 -> (batch, j-half) [XCD-locality swizzle], bx>>3 -> 64-row Q tile.
// Writes unnormalized O (bf16, scrambled [b][c][i] layout) + per-row (m,l).
__global__ __launch_bounds__(512, 2) void k_flash(const unsigned short* __restrict__ Qb,
                                                  const unsigned short* __restrict__ Kb,
                                                  const unsigned short* __restrict__ Vt,
                                                  unsigned short* __restrict__ Op,
                                                  float* __restrict__ ml) {
    __shared__ __align__(16) unsigned short Qs[64 * 72];
    __shared__ __align__(16) float          Ss[64 * 132];
    __shared__ __align__(16) unsigned short Ps[64 * 136];
    __shared__ float m_s[64], l_s[64], al_s[64];

    const int tid  = threadIdx.x;
    const int lane = tid & 63;
    const int w    = tid >> 6;
    const int col  = lane & 15, quad = lane >> 4;
    const int xcd  = blockIdx.x & 7;
    const int b    = xcd >> 1;
    const int jh   = xcd & 1;
    const int i0   = (blockIdx.x >> 3) * 64;

    const unsigned short* Qbase = Qb + (b * 4096 + i0) * 64;
    const unsigned short* Kbase = Kb + b * 4096 * 64;
    const unsigned short* Vbase = Vt + b * 512 * 4096;

    if (tid < 64) { m_s[tid] = -3.0e38f; l_s[tid] = 0.0f; }
    {   // stage Q tile (coalesced 16B per thread)
        int row = tid >> 3, ch = tid & 7;
        *(ushort8*)(&Qs[row * 72 + ch * 8]) = *(const ushort8*)(Qbase + row * 64 + ch * 8);
    }
    __syncthreads();

    bf16x8 qf[4][2];
#pragma unroll
    for (int it = 0; it < 4; ++it) {
        qf[it][0] = *(const bf16x8*)(&Qs[(it * 16 + col) * 72 + quad * 8]);
        qf[it][1] = *(const bf16x8*)(&Qs[(it * 16 + col) * 72 + 32 + quad * 8]);
    }

    f32x4 acc[4][4] = {};

    for (int jj = 0; jj < 16; ++jj) {
        const int j0 = jh * 2048 + jj * 128;
        // prefetch V B-fragments for the PV stage
        bf16x8 vf[4][4];
#pragma unroll
        for (int ct = 0; ct < 4; ++ct) {
            const unsigned short* vp = Vbase + (w * 64 + ct * 16 + col) * 4096 + j0 + quad * 8;
#pragma unroll
            for (int kk = 0; kk < 4; ++kk) vf[ct][kk] = *(const bf16x8*)(vp + kk * 32);
        }
        // ---- S = Q.K^T : wave w computes score cols [j0+16w, j0+16w+16) ----
        {
            const unsigned short* kp = Kbase + (j0 + w * 16 + col) * 64 + quad * 8;
            bf16x8 kf0 = *(const bf16x8*)(kp);
            bf16x8 kf1 = *(const bf16x8*)(kp + 32);
#pragma unroll
            for (int it = 0; it < 4; ++it) {
                f32x4 s = {};
                s = MFMA16(qf[it][0], kf0, s);
                s = MFMA16(qf[it][1], kf1, s);
                int rb = it * 16 + quad * 4;
#pragma unroll
                for (int r = 0; r < 4; ++r) Ss[(rb + r) * 132 + w * 16 + col] = s[r];
            }
        }
        __syncthreads();
        // ---- online softmax over the 64x128 tile (8 threads per row) ----
        {
            int row = tid >> 3, g = tid & 7;
            float* sp = &Ss[row * 132 + g * 16];
            f32x4 v0 = *(f32x4*)(sp + 0);
            f32x4 v1 = *(f32x4*)(sp + 4);
            f32x4 v2 = *(f32x4*)(sp + 8);
            f32x4 v3 = *(f32x4*)(sp + 12);
            float mx = fmaxf(fmaxf(fmaxf(v0[0], v0[1]), fmaxf(v0[2], v0[3])),
                             fmaxf(fmaxf(v1[0], v1[1]), fmaxf(v1[2], v1[3])));
            mx = fmaxf(mx, fmaxf(fmaxf(fmaxf(v2[0], v2[1]), fmaxf(v2[2], v2[3])),
                                 fmaxf(fmaxf(v3[0], v3[1]), fmaxf(v3[2], v3[3]))));
            mx = fmaxf(mx, __shfl_xor(mx, 1, 8));
            mx = fmaxf(mx, __shfl_xor(mx, 2, 8));
            mx = fmaxf(mx, __shfl_xor(mx, 4, 8));
            float mo = m_s[row];
            float mn = fmaxf(mo, mx);
            float al = __expf(mo - mn);
            f32x4 e0, e1, e2, e3;
#pragma unroll
            for (int i = 0; i < 4; ++i) {
                e0[i] = __expf(v0[i] - mn); e1[i] = __expf(v1[i] - mn);
                e2[i] = __expf(v2[i] - mn); e3[i] = __expf(v3[i] - mn);
            }
            float sum = (e0[0]+e0[1]+e0[2]+e0[3]) + (e1[0]+e1[1]+e1[2]+e1[3])
                      + (e2[0]+e2[1]+e2[2]+e2[3]) + (e3[0]+e3[1]+e3[2]+e3[3]);
            ushort8 p0, p1;
#pragma unroll
            for (int i = 0; i < 4; ++i) {
                p0[i]     = f2bf(e0[i]); p0[i + 4] = f2bf(e1[i]);
                p1[i]     = f2bf(e2[i]); p1[i + 4] = f2bf(e3[i]);
            }
            *(ushort8*)(&Ps[row * 136 + g * 16])     = p0;
            *(ushort8*)(&Ps[row * 136 + g * 16 + 8]) = p1;
            sum += __shfl_xor(sum, 1, 8);
            sum += __shfl_xor(sum, 2, 8);
            sum += __shfl_xor(sum, 4, 8);
            if (g == 0) { m_s[row] = mn; l_s[row] = al * l_s[row] + sum; al_s[row] = al; }
        }
        __syncthreads();
        // ---- rescale O and accumulate P.V ----
#pragma unroll
        for (int it = 0; it < 4; ++it) {
            int rb = it * 16 + quad * 4;
            f32x4 av;
            av[0] = al_s[rb]; av[1] = al_s[rb + 1]; av[2] = al_s[rb + 2]; av[3] = al_s[rb + 3];
#pragma unroll
            for (int ct = 0; ct < 4; ++ct) acc[it][ct] *= av;
        }
#pragma unroll
        for (int it = 0; it < 4; ++it) {
            bf16x8 pf[4];
#pragma unroll
            for (int kk = 0; kk < 4; ++kk)
                pf[kk] = *(const bf16x8*)(&Ps[(it * 16 + col) * 136 + kk * 32 + quad * 8]);
#pragma unroll
            for (int ct = 0; ct < 4; ++ct)
#pragma unroll
                for (int kk = 0; kk < 4; ++kk)
                    acc[it][ct] = MFMA16(pf[kk], vf[ct][kk], acc[it][ct]);
        }
    }

    // ---- epilogue: store unnormalized partial O (bf16) + (m,l) per row ----
    unsigned short* obh = Op + jh * 8388608 + b * 2097152;
#pragma unroll
    for (int it = 0; it < 4; ++it) {
        int rb = it * 16 + quad * 4;
#pragma unroll
        for (int ct = 0; ct < 4; ++ct) {
            int cg = w * 64 + ct * 16 + col;
            int f = cg * 4096 + i0 + rb;
            ushort4v pk;
            f32x4 a = acc[it][ct];
#pragma unroll
            for (int r = 0; r < 4; ++r) pk[r] = f2bf(a[r]);
            *(ushort4v*)(obh + f) = pk;
        }
    }
    if (tid < 64) {
        float2 v; v.x = m_s[tid]; v.y = l_s[tid];
        ((float2*)ml)[(jh * 4 + b) * 4096 + i0 + tid] = v;
    }
}

// ------------- kernel 4: per-row combine weights c0,c1 (folds gamma) --------
__global__ void k_mlw(const float* __restrict__ ml, const float* __restrict__ gamma,
                      float* __restrict__ cw) {
    int t = blockIdx.x * 256 + threadIdx.x;        // 16384 rows (b,i)
    float2 a = ((const float2*)ml)[t];             // jh = 0 : (m0, l0)
    float2 c = ((const float2*)ml)[16384 + t];     // jh = 1 : (m1, l1)
    float M = fmaxf(a.x, c.x);
    float e0 = __expf(a.x - M), e1 = __expf(c.x - M);
    float g = gamma[0] / (e0 * a.y + e1 * c.y);
    float2 o; o.x = g * e0; o.y = g * e1;
    ((float2*)cw)[t] = o;
}

// ------------- kernel 5: combine halves + residual (memory-bound) -----------
// out has 8388608 floats = 2097152 f32x4 groups -> grid 8192 x 256 threads.
__global__ void k_combine(const unsigned short* __restrict__ Op,
                          const float* __restrict__ cw,
                          const float* __restrict__ x, float* __restrict__ out) {
    int t = blockIdx.x * 256 + threadIdx.x;        // 0 .. 2097151
    int f = t << 2;                                // flat float index into out
    int b = f >> 21, i = f & 4095;                 // i = attention row (raw reshape)
    const float* cwf = cw + (((b << 12) + i) << 1);
    f32x4 wa = *(const f32x4*)(cwf);               // c0_i, c1_i, c0_i1, c1_i1
    f32x4 wb = *(const f32x4*)(cwf + 4);
    ushort4v o0 = *(const ushort4v*)(Op + f);
    ushort4v o1 = *(const ushort4v*)(Op + 8388608 + f);
    f32x4 xv = *(const f32x4*)(x + f);
    f32x4 o;
    o[0] = wa[0] * bf2f(o0[0]) + wa[1] * bf2f(o1[0]) + xv[0];
    o[1] = wa[2] * bf2f(o0[1]) + wa[3] * bf2f(o1[1]) + xv[1];
    o[2] = wb[0] * bf2f(o0[2]) + wb[1] * bf2f(o1[2]) + xv[2];
    o[3] = wb[2] * bf2f(o0[3]) + wb[3] * bf2f(o1[3]) + xv[3];
    *(f32x4*)(out + f) = o;
}

extern "C" void kernel_launch(void* const* d_in, const int* in_sizes, int n_in,
                              void* d_out, int out_size, void* d_ws, size_t ws_size,
                              hipStream_t stream) {
    const float* x  = (const float*)d_in[0];
    const float* W1 = (const float*)d_in[1];
    const float* W2 = (const float*)d_in[2];
    const float* W3 = (const float*)d_in[3];
    const float* gm = (const float*)d_in[4];
    float* out = (float*)d_out;

    char* ws = (char*)d_ws;
    unsigned short* Wt = (unsigned short*)(ws);                    // 640 KiB @ 0
    unsigned short* Qb = (unsigned short*)(ws + (1u  << 20));      // 2 MiB
    unsigned short* Kb = (unsigned short*)(ws + (3u  << 20));      // 2 MiB
    unsigned short* Vt = (unsigned short*)(ws + (5u  << 20));      // 16 MiB
    unsigned short* Op = (unsigned short*)(ws + (21u << 20));      // 32 MiB (2 halves)
    float*          ml = (float*)        (ws + (53u << 20));       // 256 KiB
    float*          cw = (float*)        (ws + (53u << 20) + 262144); // 128 KiB
    // total workspace use: ~53.4 MB

    hipLaunchKernelGGL(k_build_wt, dim3(1280), dim3(256), 0, stream, W1, W2, W3, Wt);
    hipLaunchKernelGGL(k_proj,     dim3(256),  dim3(512), 0, stream, x, Wt, Qb, Kb, Vt);
    hipLaunchKernelGGL(k_flash,    dim3(512),  dim3(512), 0, stream, Qb, Kb, Vt, Op, ml);
    hipLaunchKernelGGL(k_mlw,      dim3(64),   dim3(256), 0, stream, ml, gm, cw);
    hipLaunchKernelGGL(k_combine,  dim3(8192), dim3(256), 0, stream, Op, cw, x, out);
}